// Round 1
// baseline (1686.362 us; speedup 1.0000x reference)
//
#include <hip/hip_runtime.h>
#include <hip/hip_bf16.h>

// Problem: B=4, S=2048, D=512, fp32 q,k,v (v unused).
// qk = q@k^T ; attn = softmax(0.125*qk, axis=-1) ; out = attn@qk  (fp32 out)
// ws layout: [qk bf16: B*S*S][attn bf16: B*S*S] = 67 MB total.

#define SS 2048
#define DD 512
#define BATCH 4

__global__ __launch_bounds__(256) void qk_gemm(const float* __restrict__ q,
                                               const float* __restrict__ k,
                                               __hip_bfloat16* __restrict__ qk) {
    const int b  = blockIdx.z;
    const int s0 = blockIdx.y * 64;
    const int t0 = blockIdx.x * 64;
    const float* qb = q + (size_t)b * SS * DD;
    const float* kb = k + (size_t)b * SS * DD;
    __hip_bfloat16* qkb = qk + (size_t)b * SS * SS;

    __shared__ float As[64][17];   // +1 pad: inner reads are <=2-way bank aliased
    __shared__ float Bs[64][17];

    const int tid = threadIdx.x;
    const int tx = tid & 15;
    const int ty = tid >> 4;

    float acc[4][4] = {};

    for (int k0 = 0; k0 < DD; k0 += 16) {
#pragma unroll
        for (int l = 0; l < 4; ++l) {
            int idx = tid + l * 256;          // 0..1023
            int i  = idx >> 4;
            int kk = idx & 15;
            As[i][kk] = qb[(size_t)(s0 + i) * DD + k0 + kk];
            Bs[i][kk] = kb[(size_t)(t0 + i) * DD + k0 + kk];
        }
        __syncthreads();
#pragma unroll
        for (int kk = 0; kk < 16; ++kk) {
            float a[4], bb[4];
#pragma unroll
            for (int e = 0; e < 4; ++e) a[e]  = As[ty * 4 + e][kk];
#pragma unroll
            for (int e = 0; e < 4; ++e) bb[e] = Bs[tx * 4 + e][kk];
#pragma unroll
            for (int ia = 0; ia < 4; ++ia)
#pragma unroll
                for (int jb = 0; jb < 4; ++jb)
                    acc[ia][jb] += a[ia] * bb[jb];
        }
        __syncthreads();
    }
#pragma unroll
    for (int ia = 0; ia < 4; ++ia)
#pragma unroll
        for (int jb = 0; jb < 4; ++jb)
            qkb[(size_t)(s0 + ty * 4 + ia) * SS + (t0 + tx * 4 + jb)] =
                __float2bfloat16(acc[ia][jb]);
}

__global__ __launch_bounds__(256) void softmax_rows(const __hip_bfloat16* __restrict__ qk,
                                                    __hip_bfloat16* __restrict__ attn) {
    const size_t row = blockIdx.x;                 // 0 .. BATCH*SS-1
    const __hip_bfloat16* x = qk + row * SS;
    __hip_bfloat16* y = attn + row * SS;
    const int tid = threadIdx.x;
    const float SCALE = 0.125f;

    float v[8];
#pragma unroll
    for (int j = 0; j < 8; ++j)
        v[j] = SCALE * __bfloat162float(x[tid + j * 256]);

    float m = -1e30f;
#pragma unroll
    for (int j = 0; j < 8; ++j) m = fmaxf(m, v[j]);
#pragma unroll
    for (int off = 32; off > 0; off >>= 1)
        m = fmaxf(m, __shfl_down(m, off, 64));
    __shared__ float redm[4];
    if ((tid & 63) == 0) redm[tid >> 6] = m;
    __syncthreads();
    const float mAll = fmaxf(fmaxf(redm[0], redm[1]), fmaxf(redm[2], redm[3]));

    float s = 0.f;
#pragma unroll
    for (int j = 0; j < 8; ++j) { v[j] = __expf(v[j] - mAll); s += v[j]; }
#pragma unroll
    for (int off = 32; off > 0; off >>= 1)
        s += __shfl_down(s, off, 64);
    __shared__ float reds[4];
    if ((tid & 63) == 0) reds[tid >> 6] = s;
    __syncthreads();
    const float inv = 1.0f / (reds[0] + reds[1] + reds[2] + reds[3]);
#pragma unroll
    for (int j = 0; j < 8; ++j)
        y[tid + j * 256] = __float2bfloat16(v[j] * inv);
}

__global__ __launch_bounds__(256) void av_gemm(const __hip_bfloat16* __restrict__ attn,
                                               const __hip_bfloat16* __restrict__ qk,
                                               float* __restrict__ out) {
    const int b  = blockIdx.z;
    const int s0 = blockIdx.y * 64;
    const int t0 = blockIdx.x * 64;
    const __hip_bfloat16* ab = attn + (size_t)b * SS * SS;
    const __hip_bfloat16* vb = qk   + (size_t)b * SS * SS;
    float* ob = out + (size_t)b * SS * SS;

    __shared__ float As[64][17];
    __shared__ float Bs[16][65];

    const int tid = threadIdx.x;
    const int tx = tid & 15;
    const int ty = tid >> 4;

    float acc[4][4] = {};

    for (int u0 = 0; u0 < SS; u0 += 16) {
#pragma unroll
        for (int l = 0; l < 4; ++l) {
            int idx = tid + l * 256;
            int i  = idx >> 4;
            int kk = idx & 15;
            As[i][kk] = __bfloat162float(ab[(size_t)(s0 + i) * SS + u0 + kk]);
            int r = idx >> 6;
            int c = idx & 63;
            Bs[r][c] = __bfloat162float(vb[(size_t)(u0 + r) * SS + t0 + c]);
        }
        __syncthreads();
#pragma unroll
        for (int kk = 0; kk < 16; ++kk) {
            float a[4], bb[4];
#pragma unroll
            for (int e = 0; e < 4; ++e) a[e]  = As[ty * 4 + e][kk];
#pragma unroll
            for (int e = 0; e < 4; ++e) bb[e] = Bs[kk][tx * 4 + e];
#pragma unroll
            for (int ia = 0; ia < 4; ++ia)
#pragma unroll
                for (int jb = 0; jb < 4; ++jb)
                    acc[ia][jb] += a[ia] * bb[jb];
        }
        __syncthreads();
    }
#pragma unroll
    for (int ia = 0; ia < 4; ++ia)
#pragma unroll
        for (int jb = 0; jb < 4; ++jb)
            ob[(size_t)(s0 + ty * 4 + ia) * SS + (t0 + tx * 4 + jb)] = acc[ia][jb];
}

extern "C" void kernel_launch(void* const* d_in, const int* in_sizes, int n_in,
                              void* d_out, int out_size, void* d_ws, size_t ws_size,
                              hipStream_t stream) {
    const float* q = (const float*)d_in[0];
    const float* k = (const float*)d_in[1];
    // d_in[2] (v) is unused by the reference math.
    float* out = (float*)d_out;

    __hip_bfloat16* qk   = (__hip_bfloat16*)d_ws;
    __hip_bfloat16* attn = qk + (size_t)BATCH * SS * SS;

    dim3 g(SS / 64, SS / 64, BATCH);
    qk_gemm<<<g, 256, 0, stream>>>(q, k, qk);
    softmax_rows<<<dim3(BATCH * SS), 256, 0, stream>>>(qk, attn);
    av_gemm<<<g, 256, 0, stream>>>(attn, qk, out);
}

// Round 2
// 266.254 us; speedup vs baseline: 6.3337x; 6.3337x over previous
//
#include <hip/hip_runtime.h>
#include <hip/hip_bf16.h>
#include <stdint.h>

// qk = q@k^T ; attn = softmax(0.125*qk) in-place over qk ; out = attn @ qk_raw
// ws: [qk bf16 32MiB][qkT bf16 32MiB] = 64MiB exactly (round-1 proved ws >= 64MiB).
// GEMM1: compensated bf16 MFMA (hi/lo, 3 passes) ~= fp32 accuracy.
// GEMM2: m97 structure — 128x128 tile, BK=32, global_load_lds width 16.

#define SS 2048
#define DD 512
#define BATCH 4

typedef __attribute__((ext_vector_type(8))) short short8;
typedef __attribute__((ext_vector_type(4))) float floatx4;
typedef __attribute__((ext_vector_type(4))) float float4v;
typedef __attribute__((ext_vector_type(4))) unsigned int uintx4;

#define GLOBAL_AS const __attribute__((address_space(1)))
#define LDS_AS __attribute__((address_space(3)))

__device__ __forceinline__ float bf2f(uint32_t hbits) {
    union { uint32_t u; float f; } c; c.u = hbits << 16; return c.f;
}
__device__ __forceinline__ uint32_t f2bf_rne(float f) {
    union { float f; uint32_t u; } c; c.f = f;
    return (c.u + 0x7fffu + ((c.u >> 16) & 1u)) >> 16;
}

union PackU { uint32_t u[4]; short8 s8; };

// ---------------------------------------------------------------- GEMM1
// qk[s][t] = sum_d q[s][d]*k[t][d]  (fp32-grade via hi/lo bf16, 3 MFMA passes)
// writes qk (row-major bf16) and qkT (transposed bf16)
__global__ __launch_bounds__(256, 2) void gemm1_kernel(
    const float* __restrict__ Q, const float* __restrict__ K,
    uint16_t* __restrict__ qk, uint16_t* __restrict__ qkT)
{
    const int b  = blockIdx.z;
    const int s0 = blockIdx.y * 128;
    const int t0 = blockIdx.x * 128;
    const float* qb = Q + (size_t)b * SS * DD;
    const float* kb = K + (size_t)b * SS * DD;

    __shared__ uint16_t Ahi[128 * 32];
    __shared__ uint16_t Alo[128 * 32];
    __shared__ uint16_t Bhi[128 * 32];
    __shared__ uint16_t Blo[128 * 32];

    const int tid  = threadIdx.x;
    const int lane = tid & 63;
    const int wave = tid >> 6;
    const int wm   = wave >> 1;
    const int wn   = wave & 1;
    const int fm   = lane & 15;
    const int quad = lane >> 4;

    floatx4 acc[4][4];
#pragma unroll
    for (int i = 0; i < 4; ++i)
#pragma unroll
        for (int j = 0; j < 4; ++j)
            acc[i][j] = (floatx4)0.0f;

    const int r  = tid >> 1;          // staging row 0..127
    const int c0 = (tid & 1) * 16;    // staging col chunk
    const float* gA = qb + (size_t)(s0 + r) * DD + c0;
    const float* gB = kb + (size_t)(t0 + r) * DD + c0;

    for (int k0 = 0; k0 < DD; k0 += 32) {
        float4v a4[4], b4[4];
#pragma unroll
        for (int l = 0; l < 4; ++l) {
            a4[l] = *(const float4v*)(gA + k0 + l * 4);
            b4[l] = *(const float4v*)(gB + k0 + l * 4);
        }
        uint32_t hiA[8], loA[8], hiB[8], loB[8];
#pragma unroll
        for (int l = 0; l < 4; ++l) {
#pragma unroll
            for (int e = 0; e < 4; e += 2) {
                int idx = (4 * l + e) >> 1;
                {
                    float f0 = a4[l][e], f1 = a4[l][e + 1];
                    uint32_t h0 = __float_as_uint(f0) >> 16;
                    uint32_t h1 = __float_as_uint(f1) >> 16;
                    float l0 = f0 - bf2f(h0);
                    float l1 = f1 - bf2f(h1);
                    uint32_t lo0 = __float_as_uint(l0) >> 16;
                    uint32_t lo1 = __float_as_uint(l1) >> 16;
                    hiA[idx] = h0 | (h1 << 16);
                    loA[idx] = lo0 | (lo1 << 16);
                }
                {
                    float f0 = b4[l][e], f1 = b4[l][e + 1];
                    uint32_t h0 = __float_as_uint(f0) >> 16;
                    uint32_t h1 = __float_as_uint(f1) >> 16;
                    float l0 = f0 - bf2f(h0);
                    float l1 = f1 - bf2f(h1);
                    uint32_t lo0 = __float_as_uint(l0) >> 16;
                    uint32_t lo1 = __float_as_uint(l1) >> 16;
                    hiB[idx] = h0 | (h1 << 16);
                    loB[idx] = lo0 | (lo1 << 16);
                }
            }
        }
        __syncthreads();   // previous iteration's LDS reads complete
        {
            PackU p;
            p.u[0]=hiA[0]; p.u[1]=hiA[1]; p.u[2]=hiA[2]; p.u[3]=hiA[3];
            *(short8*)(&Ahi[r * 32 + c0]) = p.s8;
            p.u[0]=hiA[4]; p.u[1]=hiA[5]; p.u[2]=hiA[6]; p.u[3]=hiA[7];
            *(short8*)(&Ahi[r * 32 + c0 + 8]) = p.s8;
            p.u[0]=loA[0]; p.u[1]=loA[1]; p.u[2]=loA[2]; p.u[3]=loA[3];
            *(short8*)(&Alo[r * 32 + c0]) = p.s8;
            p.u[0]=loA[4]; p.u[1]=loA[5]; p.u[2]=loA[6]; p.u[3]=loA[7];
            *(short8*)(&Alo[r * 32 + c0 + 8]) = p.s8;
            p.u[0]=hiB[0]; p.u[1]=hiB[1]; p.u[2]=hiB[2]; p.u[3]=hiB[3];
            *(short8*)(&Bhi[r * 32 + c0]) = p.s8;
            p.u[0]=hiB[4]; p.u[1]=hiB[5]; p.u[2]=hiB[6]; p.u[3]=hiB[7];
            *(short8*)(&Bhi[r * 32 + c0 + 8]) = p.s8;
            p.u[0]=loB[0]; p.u[1]=loB[1]; p.u[2]=loB[2]; p.u[3]=loB[3];
            *(short8*)(&Blo[r * 32 + c0]) = p.s8;
            p.u[0]=loB[4]; p.u[1]=loB[5]; p.u[2]=loB[6]; p.u[3]=loB[7];
            *(short8*)(&Blo[r * 32 + c0 + 8]) = p.s8;
        }
        __syncthreads();

        short8 fahi[4], falo[4], fbhi[4], fblo[4];
#pragma unroll
        for (int mt = 0; mt < 4; ++mt) {
            int off = (wm * 64 + mt * 16 + fm) * 32 + quad * 8;
            fahi[mt] = *(const short8*)(&Ahi[off]);
            falo[mt] = *(const short8*)(&Alo[off]);
        }
#pragma unroll
        for (int nt = 0; nt < 4; ++nt) {
            int off = (wn * 64 + nt * 16 + fm) * 32 + quad * 8;
            fbhi[nt] = *(const short8*)(&Bhi[off]);
            fblo[nt] = *(const short8*)(&Blo[off]);
        }
#pragma unroll
        for (int mt = 0; mt < 4; ++mt)
#pragma unroll
            for (int nt = 0; nt < 4; ++nt) {
                acc[mt][nt] = __builtin_amdgcn_mfma_f32_16x16x32_bf16(fahi[mt], fbhi[nt], acc[mt][nt], 0, 0, 0);
                acc[mt][nt] = __builtin_amdgcn_mfma_f32_16x16x32_bf16(fahi[mt], fblo[nt], acc[mt][nt], 0, 0, 0);
                acc[mt][nt] = __builtin_amdgcn_mfma_f32_16x16x32_bf16(falo[mt], fbhi[nt], acc[mt][nt], 0, 0, 0);
            }
    }

    uint16_t* qkb  = qk  + (size_t)b * SS * SS;
    uint16_t* qkTb = qkT + (size_t)b * SS * SS;
#pragma unroll
    for (int mt = 0; mt < 4; ++mt) {
#pragma unroll
        for (int nt = 0; nt < 4; ++nt) {
            const int srow = s0 + wm * 64 + mt * 16 + quad * 4;
            const int tcol = t0 + wn * 64 + nt * 16 + fm;
            uint32_t b0 = f2bf_rne(acc[mt][nt][0]);
            uint32_t b1 = f2bf_rne(acc[mt][nt][1]);
            uint32_t b2 = f2bf_rne(acc[mt][nt][2]);
            uint32_t b3 = f2bf_rne(acc[mt][nt][3]);
            qkb[(size_t)(srow + 0) * SS + tcol] = (uint16_t)b0;
            qkb[(size_t)(srow + 1) * SS + tcol] = (uint16_t)b1;
            qkb[(size_t)(srow + 2) * SS + tcol] = (uint16_t)b2;
            qkb[(size_t)(srow + 3) * SS + tcol] = (uint16_t)b3;
            uint2 pk = make_uint2(b0 | (b1 << 16), b2 | (b3 << 16));
            *(uint2*)(&qkTb[(size_t)tcol * SS + srow]) = pk;
        }
    }
}

// ---------------------------------------------------------------- softmax
// in-place: qk row -> softmax(0.125*row), bf16. qkT keeps the raw values.
__global__ __launch_bounds__(256) void softmax_inplace(uint16_t* __restrict__ qk)
{
    const size_t row = blockIdx.x;
    uint16_t* x = qk + row * SS;
    const int tid  = threadIdx.x;
    const int lane = tid & 63;
    const int wave = tid >> 6;

    uintx4 raw = *(const uintx4*)(x + tid * 8);
    float v[8];
#pragma unroll
    for (int i = 0; i < 4; ++i) {
        uint32_t u = raw[i];
        v[2 * i]     = bf2f(u & 0xffffu) * 0.125f;
        v[2 * i + 1] = bf2f(u >> 16) * 0.125f;
    }
    float m = v[0];
#pragma unroll
    for (int j = 1; j < 8; ++j) m = fmaxf(m, v[j]);
#pragma unroll
    for (int off = 1; off < 64; off <<= 1) m = fmaxf(m, __shfl_xor(m, off, 64));
    __shared__ float red[8];
    if (lane == 0) red[wave] = m;
    __syncthreads();
    m = fmaxf(fmaxf(red[0], red[1]), fmaxf(red[2], red[3]));

    float s = 0.f;
#pragma unroll
    for (int j = 0; j < 8; ++j) { v[j] = __expf(v[j] - m); s += v[j]; }
#pragma unroll
    for (int off = 1; off < 64; off <<= 1) s += __shfl_xor(s, off, 64);
    if (lane == 0) red[4 + wave] = s;
    __syncthreads();
    s = (red[4] + red[5]) + (red[6] + red[7]);
    const float inv = 1.0f / s;
#pragma unroll
    for (int i = 0; i < 4; ++i)
        raw[i] = f2bf_rne(v[2 * i] * inv) | (f2bf_rne(v[2 * i + 1] * inv) << 16);
    *(uintx4*)(x + tid * 8) = raw;
}

// ---------------------------------------------------------------- GEMM2
// out[s][t] = sum_u attn[s][u] * qkT[t][u]   (m97 structure)
__global__ __launch_bounds__(256, 2) void gemm2_kernel(
    const uint16_t* __restrict__ attn, const uint16_t* __restrict__ qkT,
    float* __restrict__ out)
{
    const int b  = blockIdx.z;
    const int s0 = blockIdx.y * 128;
    const int t0 = blockIdx.x * 128;
    const uint16_t* ab = attn + (size_t)b * SS * SS;
    const uint16_t* bb = qkT  + (size_t)b * SS * SS;

    __shared__ uint16_t As[128 * 32];
    __shared__ uint16_t Bs[128 * 32];

    const int tid  = threadIdx.x;
    const int lane = tid & 63;
    const int wave = tid >> 6;
    const int wm = wave >> 1, wn = wave & 1;
    const int fm = lane & 15, quad = lane >> 4;

    floatx4 acc[4][4];
#pragma unroll
    for (int i = 0; i < 4; ++i)
#pragma unroll
        for (int j = 0; j < 4; ++j)
            acc[i][j] = (floatx4)0.0f;

    // staging: chunk c = wave*128 + l*64 + lane; r = c>>2; p = c&3
    const int c0i = wave * 128 + lane;
    const int c1i = c0i + 64;
    const int rA0 = c0i >> 2, pA0 = c0i & 3;
    const int rA1 = c1i >> 2, pA1 = c1i & 3;
    uint16_t* ldsA0 = &As[(wave * 128) * 8];
    uint16_t* ldsA1 = &As[(wave * 128 + 64) * 8];
    uint16_t* ldsB0 = &Bs[(wave * 128) * 8];
    uint16_t* ldsB1 = &Bs[(wave * 128 + 64) * 8];

    for (int k0 = 0; k0 < SS; k0 += 32) {
        __syncthreads();   // previous iteration's LDS reads complete
        __builtin_amdgcn_global_load_lds(
            (GLOBAL_AS void*)(ab + (size_t)(s0 + rA0) * SS + k0 + pA0 * 8),
            (LDS_AS void*)ldsA0, 16, 0, 0);
        __builtin_amdgcn_global_load_lds(
            (GLOBAL_AS void*)(ab + (size_t)(s0 + rA1) * SS + k0 + pA1 * 8),
            (LDS_AS void*)ldsA1, 16, 0, 0);
        __builtin_amdgcn_global_load_lds(
            (GLOBAL_AS void*)(bb + (size_t)(t0 + rA0) * SS + k0 + pA0 * 8),
            (LDS_AS void*)ldsB0, 16, 0, 0);
        __builtin_amdgcn_global_load_lds(
            (GLOBAL_AS void*)(bb + (size_t)(t0 + rA1) * SS + k0 + pA1 * 8),
            (LDS_AS void*)ldsB1, 16, 0, 0);
        __syncthreads();   // drains vmcnt -> data resident in LDS

        short8 fa[4], fb[4];
#pragma unroll
        for (int mt = 0; mt < 4; ++mt)
            fa[mt] = *(const short8*)(&As[(wm * 64 + mt * 16 + fm) * 32 + quad * 8]);
#pragma unroll
        for (int nt = 0; nt < 4; ++nt)
            fb[nt] = *(const short8*)(&Bs[(wn * 64 + nt * 16 + fm) * 32 + quad * 8]);
#pragma unroll
        for (int mt = 0; mt < 4; ++mt)
#pragma unroll
            for (int nt = 0; nt < 4; ++nt)
                acc[mt][nt] = __builtin_amdgcn_mfma_f32_16x16x32_bf16(fa[mt], fb[nt], acc[mt][nt], 0, 0, 0);
    }

    float* ob = out + (size_t)b * SS * SS;
#pragma unroll
    for (int mt = 0; mt < 4; ++mt) {
#pragma unroll
        for (int nt = 0; nt < 4; ++nt) {
            const int srow = s0 + wm * 64 + mt * 16 + quad * 4;
            const int tcol = t0 + wn * 64 + nt * 16 + fm;
#pragma unroll
            for (int reg = 0; reg < 4; ++reg)
                ob[(size_t)(srow + reg) * SS + tcol] = acc[mt][nt][reg];
        }
    }
}

extern "C" void kernel_launch(void* const* d_in, const int* in_sizes, int n_in,
                              void* d_out, int out_size, void* d_ws, size_t ws_size,
                              hipStream_t stream) {
    const float* q = (const float*)d_in[0];
    const float* k = (const float*)d_in[1];
    float* out = (float*)d_out;

    uint16_t* qk  = (uint16_t*)d_ws;
    uint16_t* qkT = qk + (size_t)BATCH * SS * SS;

    dim3 grid(SS / 128, SS / 128, BATCH);
    gemm1_kernel<<<grid, 256, 0, stream>>>(q, k, qk, qkT);
    softmax_inplace<<<dim3(BATCH * SS), 256, 0, stream>>>(qk);
    gemm2_kernel<<<grid, 256, 0, stream>>>(qk, qkT, out);
}

// Round 3
// 241.533 us; speedup vs baseline: 6.9819x; 1.1023x over previous
//
#include <hip/hip_runtime.h>
#include <hip/hip_bf16.h>
#include <stdint.h>

// qk = q@k^T ; attn = softmax(0.125*qk) in-place over qk ; out = attn @ qk_raw
// ws: [qk bf16 33.5MB][qkT bf16 33.5MB] = 67 MB (proven available in round 1).
// GEMM1: single-pass fp16 MFMA (q,k ~ N(0,1): fp16 dot error ~0.015 abs on qk,
//        an order below the bf16 storage rounding of qk that dominates absmax).
// GEMM2: m97 structure + 4x4 supertile swizzle for L2 locality.

#define SS 2048
#define DD 512
#define BATCH 4

typedef __attribute__((ext_vector_type(8))) short short8;
typedef __attribute__((ext_vector_type(8))) _Float16 half8;
typedef __attribute__((ext_vector_type(4))) float floatx4;
typedef __attribute__((ext_vector_type(4))) float float4v;
typedef __attribute__((ext_vector_type(4))) unsigned int uintx4;

#define GLOBAL_AS const __attribute__((address_space(1)))
#define LDS_AS __attribute__((address_space(3)))

__device__ __forceinline__ float bf2f(uint32_t hbits) {
    union { uint32_t u; float f; } c; c.u = hbits << 16; return c.f;
}
__device__ __forceinline__ uint32_t f2bf_rne(float f) {
    union { float f; uint32_t u; } c; c.f = f;
    return (c.u + 0x7fffu + ((c.u >> 16) & 1u)) >> 16;
}
__device__ __forceinline__ uint32_t pk2h(float x, float y) {
    _Float16 hx = (_Float16)x, hy = (_Float16)y;   // RNE v_cvt_f16_f32
    union { _Float16 h; uint16_t u; } cx, cy;
    cx.h = hx; cy.h = hy;
    return (uint32_t)cx.u | ((uint32_t)cy.u << 16);
}

union PackU { uint32_t u[4]; short8 s8; };

// ---------------------------------------------------------------- GEMM1
// qk[s][t] = sum_d q[s][d]*k[t][d]  via single-pass fp16 MFMA.
// writes qk (row-major bf16) and qkT (transposed bf16)
__global__ __launch_bounds__(256, 2) void gemm1_kernel(
    const float* __restrict__ Q, const float* __restrict__ K,
    uint16_t* __restrict__ qk, uint16_t* __restrict__ qkT)
{
    const int b  = blockIdx.z;
    const int s0 = blockIdx.y * 128;
    const int t0 = blockIdx.x * 128;
    const float* qb = Q + (size_t)b * SS * DD;
    const float* kb = K + (size_t)b * SS * DD;

    __shared__ uint16_t Ah[128 * 32];
    __shared__ uint16_t Bh[128 * 32];

    const int tid  = threadIdx.x;
    const int lane = tid & 63;
    const int wave = tid >> 6;
    const int wm   = wave >> 1;
    const int wn   = wave & 1;
    const int fm   = lane & 15;
    const int quad = lane >> 4;

    floatx4 acc[4][4];
#pragma unroll
    for (int i = 0; i < 4; ++i)
#pragma unroll
        for (int j = 0; j < 4; ++j)
            acc[i][j] = (floatx4)0.0f;

    const int r  = tid >> 1;          // staging row 0..127
    const int c0 = (tid & 1) * 16;    // staging col chunk
    const float* gA = qb + (size_t)(s0 + r) * DD + c0;
    const float* gB = kb + (size_t)(t0 + r) * DD + c0;

    for (int k0 = 0; k0 < DD; k0 += 32) {
        float4v a4[4], b4[4];
#pragma unroll
        for (int l = 0; l < 4; ++l) {
            a4[l] = *(const float4v*)(gA + k0 + l * 4);
            b4[l] = *(const float4v*)(gB + k0 + l * 4);
        }
        uint32_t pa[8], pb[8];
#pragma unroll
        for (int l = 0; l < 4; ++l) {
            pa[2 * l]     = pk2h(a4[l][0], a4[l][1]);
            pa[2 * l + 1] = pk2h(a4[l][2], a4[l][3]);
            pb[2 * l]     = pk2h(b4[l][0], b4[l][1]);
            pb[2 * l + 1] = pk2h(b4[l][2], b4[l][3]);
        }
        __syncthreads();   // previous iteration's LDS reads complete
        {
            PackU p;
            p.u[0]=pa[0]; p.u[1]=pa[1]; p.u[2]=pa[2]; p.u[3]=pa[3];
            *(short8*)(&Ah[r * 32 + c0]) = p.s8;
            p.u[0]=pa[4]; p.u[1]=pa[5]; p.u[2]=pa[6]; p.u[3]=pa[7];
            *(short8*)(&Ah[r * 32 + c0 + 8]) = p.s8;
            p.u[0]=pb[0]; p.u[1]=pb[1]; p.u[2]=pb[2]; p.u[3]=pb[3];
            *(short8*)(&Bh[r * 32 + c0]) = p.s8;
            p.u[0]=pb[4]; p.u[1]=pb[5]; p.u[2]=pb[6]; p.u[3]=pb[7];
            *(short8*)(&Bh[r * 32 + c0 + 8]) = p.s8;
        }
        __syncthreads();

        half8 fa[4], fb[4];
#pragma unroll
        for (int mt = 0; mt < 4; ++mt)
            fa[mt] = *(const half8*)(&Ah[(wm * 64 + mt * 16 + fm) * 32 + quad * 8]);
#pragma unroll
        for (int nt = 0; nt < 4; ++nt)
            fb[nt] = *(const half8*)(&Bh[(wn * 64 + nt * 16 + fm) * 32 + quad * 8]);
#pragma unroll
        for (int mt = 0; mt < 4; ++mt)
#pragma unroll
            for (int nt = 0; nt < 4; ++nt)
                acc[mt][nt] = __builtin_amdgcn_mfma_f32_16x16x32_f16(fa[mt], fb[nt], acc[mt][nt], 0, 0, 0);
    }

    uint16_t* qkb  = qk  + (size_t)b * SS * SS;
    uint16_t* qkTb = qkT + (size_t)b * SS * SS;
#pragma unroll
    for (int mt = 0; mt < 4; ++mt) {
#pragma unroll
        for (int nt = 0; nt < 4; ++nt) {
            const int srow = s0 + wm * 64 + mt * 16 + quad * 4;
            const int tcol = t0 + wn * 64 + nt * 16 + fm;
            uint32_t b0 = f2bf_rne(acc[mt][nt][0]);
            uint32_t b1 = f2bf_rne(acc[mt][nt][1]);
            uint32_t b2 = f2bf_rne(acc[mt][nt][2]);
            uint32_t b3 = f2bf_rne(acc[mt][nt][3]);
            qkb[(size_t)(srow + 0) * SS + tcol] = (uint16_t)b0;
            qkb[(size_t)(srow + 1) * SS + tcol] = (uint16_t)b1;
            qkb[(size_t)(srow + 2) * SS + tcol] = (uint16_t)b2;
            qkb[(size_t)(srow + 3) * SS + tcol] = (uint16_t)b3;
            uint2 pk = make_uint2(b0 | (b1 << 16), b2 | (b3 << 16));
            *(uint2*)(&qkTb[(size_t)tcol * SS + srow]) = pk;
        }
    }
}

// ---------------------------------------------------------------- softmax
// in-place: qk row -> softmax(0.125*row), bf16. qkT keeps the raw values.
__global__ __launch_bounds__(256) void softmax_inplace(uint16_t* __restrict__ qk)
{
    const size_t row = blockIdx.x;
    uint16_t* x = qk + row * SS;
    const int tid  = threadIdx.x;
    const int lane = tid & 63;
    const int wave = tid >> 6;

    uintx4 raw = *(const uintx4*)(x + tid * 8);
    float v[8];
#pragma unroll
    for (int i = 0; i < 4; ++i) {
        uint32_t u = raw[i];
        v[2 * i]     = bf2f(u & 0xffffu) * 0.125f;
        v[2 * i + 1] = bf2f(u >> 16) * 0.125f;
    }
    float m = v[0];
#pragma unroll
    for (int j = 1; j < 8; ++j) m = fmaxf(m, v[j]);
#pragma unroll
    for (int off = 1; off < 64; off <<= 1) m = fmaxf(m, __shfl_xor(m, off, 64));
    __shared__ float red[8];
    if (lane == 0) red[wave] = m;
    __syncthreads();
    m = fmaxf(fmaxf(red[0], red[1]), fmaxf(red[2], red[3]));

    float s = 0.f;
#pragma unroll
    for (int j = 0; j < 8; ++j) { v[j] = __expf(v[j] - m); s += v[j]; }
#pragma unroll
    for (int off = 1; off < 64; off <<= 1) s += __shfl_xor(s, off, 64);
    if (lane == 0) red[4 + wave] = s;
    __syncthreads();
    s = (red[4] + red[5]) + (red[6] + red[7]);
    const float inv = 1.0f / s;
#pragma unroll
    for (int i = 0; i < 4; ++i)
        raw[i] = f2bf_rne(v[2 * i] * inv) | (f2bf_rne(v[2 * i + 1] * inv) << 16);
    *(uintx4*)(x + tid * 8) = raw;
}

// ---------------------------------------------------------------- GEMM2
// out[s][t] = sum_u attn[s][u] * qkT[t][u]   (m97 structure + supertile swizzle)
__global__ __launch_bounds__(256, 2) void gemm2_kernel(
    const uint16_t* __restrict__ attn, const uint16_t* __restrict__ qkT,
    float* __restrict__ out)
{
    const int b = blockIdx.z;
    // 4x4 supertile remap: 16 consecutive dispatch IDs cover a 4x4 tile square
    // (4 A-tiles + 4 B-tiles = 4 MB working set ~ one XCD L2).
    const int lin = blockIdx.y * 16 + blockIdx.x;     // dispatch order, x fastest
    const int sup = lin >> 4;                          // supertile 0..15
    const int inn = lin & 15;
    const int ty_ = (sup >> 2) * 4 + ((inn >> 2) & 3);
    const int tx_ = (sup & 3) * 4 + (inn & 3);
    const int s0 = ty_ * 128;
    const int t0 = tx_ * 128;

    const uint16_t* ab = attn + (size_t)b * SS * SS;
    const uint16_t* bb = qkT  + (size_t)b * SS * SS;

    __shared__ uint16_t As[128 * 32];
    __shared__ uint16_t Bs[128 * 32];

    const int tid  = threadIdx.x;
    const int lane = tid & 63;
    const int wave = tid >> 6;
    const int wm = wave >> 1, wn = wave & 1;
    const int fm = lane & 15, quad = lane >> 4;

    floatx4 acc[4][4];
#pragma unroll
    for (int i = 0; i < 4; ++i)
#pragma unroll
        for (int j = 0; j < 4; ++j)
            acc[i][j] = (floatx4)0.0f;

    const int c0i = wave * 128 + lane;
    const int c1i = c0i + 64;
    const int rA0 = c0i >> 2, pA0 = c0i & 3;
    const int rA1 = c1i >> 2, pA1 = c1i & 3;
    uint16_t* ldsA0 = &As[(wave * 128) * 8];
    uint16_t* ldsA1 = &As[(wave * 128 + 64) * 8];
    uint16_t* ldsB0 = &Bs[(wave * 128) * 8];
    uint16_t* ldsB1 = &Bs[(wave * 128 + 64) * 8];

    for (int k0 = 0; k0 < SS; k0 += 32) {
        __syncthreads();   // previous iteration's LDS reads complete
        __builtin_amdgcn_global_load_lds(
            (GLOBAL_AS void*)(ab + (size_t)(s0 + rA0) * SS + k0 + pA0 * 8),
            (LDS_AS void*)ldsA0, 16, 0, 0);
        __builtin_amdgcn_global_load_lds(
            (GLOBAL_AS void*)(ab + (size_t)(s0 + rA1) * SS + k0 + pA1 * 8),
            (LDS_AS void*)ldsA1, 16, 0, 0);
        __builtin_amdgcn_global_load_lds(
            (GLOBAL_AS void*)(bb + (size_t)(t0 + rA0) * SS + k0 + pA0 * 8),
            (LDS_AS void*)ldsB0, 16, 0, 0);
        __builtin_amdgcn_global_load_lds(
            (GLOBAL_AS void*)(bb + (size_t)(t0 + rA1) * SS + k0 + pA1 * 8),
            (LDS_AS void*)ldsB1, 16, 0, 0);
        __syncthreads();   // drains vmcnt -> data resident in LDS

        short8 fa[4], fb[4];
#pragma unroll
        for (int mt = 0; mt < 4; ++mt)
            fa[mt] = *(const short8*)(&As[(wm * 64 + mt * 16 + fm) * 32 + quad * 8]);
#pragma unroll
        for (int nt = 0; nt < 4; ++nt)
            fb[nt] = *(const short8*)(&Bs[(wn * 64 + nt * 16 + fm) * 32 + quad * 8]);
#pragma unroll
        for (int mt = 0; mt < 4; ++mt)
#pragma unroll
            for (int nt = 0; nt < 4; ++nt)
                acc[mt][nt] = __builtin_amdgcn_mfma_f32_16x16x32_bf16(fa[mt], fb[nt], acc[mt][nt], 0, 0, 0);
    }

    float* ob = out + (size_t)b * SS * SS;
#pragma unroll
    for (int mt = 0; mt < 4; ++mt) {
#pragma unroll
        for (int nt = 0; nt < 4; ++nt) {
            const int srow = s0 + wm * 64 + mt * 16 + quad * 4;
            const int tcol = t0 + wn * 64 + nt * 16 + fm;
#pragma unroll
            for (int reg = 0; reg < 4; ++reg)
                ob[(size_t)(srow + reg) * SS + tcol] = acc[mt][nt][reg];
        }
    }
}

extern "C" void kernel_launch(void* const* d_in, const int* in_sizes, int n_in,
                              void* d_out, int out_size, void* d_ws, size_t ws_size,
                              hipStream_t stream) {
    const float* q = (const float*)d_in[0];
    const float* k = (const float*)d_in[1];
    float* out = (float*)d_out;

    uint16_t* qk  = (uint16_t*)d_ws;
    uint16_t* qkT = qk + (size_t)BATCH * SS * SS;

    dim3 grid(SS / 128, SS / 128, BATCH);
    gemm1_kernel<<<grid, 256, 0, stream>>>(q, k, qk, qkT);
    softmax_inplace<<<dim3(BATCH * SS), 256, 0, stream>>>(qk);
    gemm2_kernel<<<grid, 256, 0, stream>>>(qk, qkT, out);
}

// Round 4
// 236.201 us; speedup vs baseline: 7.1395x; 1.0226x over previous
//
#include <hip/hip_runtime.h>
#include <hip/hip_bf16.h>
#include <stdint.h>

// qk = q@k^T ; attn = softmax(0.125*qk) in-place over qk ; out = attn @ qk_raw
// ws: [qk bf16 33.5MB][qkT bf16 33.5MB] = 67 MB.
// Round 4: BK=64 as two BK=32 sub-stages per barrier pair (halves the
// vmcnt(0)-drain count, the ~20% structural stall of the m97 K-loop).
// MFMA order is bit-identical to round 3 -> absmax must stay 1.3125.

#define SS 2048
#define DD 512
#define BATCH 4

typedef __attribute__((ext_vector_type(8))) short short8;
typedef __attribute__((ext_vector_type(8))) _Float16 half8;
typedef __attribute__((ext_vector_type(4))) float floatx4;
typedef __attribute__((ext_vector_type(4))) float float4v;
typedef __attribute__((ext_vector_type(4))) unsigned int uintx4;

#define GLOBAL_AS const __attribute__((address_space(1)))
#define LDS_AS __attribute__((address_space(3)))

__device__ __forceinline__ float bf2f(uint32_t hbits) {
    union { uint32_t u; float f; } c; c.u = hbits << 16; return c.f;
}
__device__ __forceinline__ uint32_t f2bf_rne(float f) {
    union { float f; uint32_t u; } c; c.f = f;
    return (c.u + 0x7fffu + ((c.u >> 16) & 1u)) >> 16;
}
__device__ __forceinline__ uint32_t pk2h(float x, float y) {
    _Float16 hx = (_Float16)x, hy = (_Float16)y;   // RNE v_cvt_f16_f32
    union { _Float16 h; uint16_t u; } cx, cy;
    cx.h = hx; cy.h = hy;
    return (uint32_t)cx.u | ((uint32_t)cy.u << 16);
}

union PackU { uint32_t u[4]; short8 s8; };

// ---------------------------------------------------------------- GEMM1
// qk[s][t] = sum_d q[s][d]*k[t][d]  via single-pass fp16 MFMA, BK=64.
// writes qk (row-major bf16) and qkT (transposed bf16)
__global__ __launch_bounds__(256, 2) void gemm1_kernel(
    const float* __restrict__ Q, const float* __restrict__ K,
    uint16_t* __restrict__ qk, uint16_t* __restrict__ qkT)
{
    const int b  = blockIdx.z;
    const int s0 = blockIdx.y * 128;
    const int t0 = blockIdx.x * 128;
    const float* qb = Q + (size_t)b * SS * DD;
    const float* kb = K + (size_t)b * SS * DD;

    __shared__ uint16_t Ah[2 * 128 * 32];   // two BK=32 sub-tiles
    __shared__ uint16_t Bh[2 * 128 * 32];

    const int tid  = threadIdx.x;
    const int lane = tid & 63;
    const int wave = tid >> 6;
    const int wm   = wave >> 1;
    const int wn   = wave & 1;
    const int fm   = lane & 15;
    const int quad = lane >> 4;

    floatx4 acc[4][4];
#pragma unroll
    for (int i = 0; i < 4; ++i)
#pragma unroll
        for (int j = 0; j < 4; ++j)
            acc[i][j] = (floatx4)0.0f;

    const int r  = tid >> 1;          // staging row 0..127
    const int c0 = (tid & 1) * 16;    // staging col chunk (fp32 elems)
    const float* gA = qb + (size_t)(s0 + r) * DD + c0;
    const float* gB = kb + (size_t)(t0 + r) * DD + c0;

    for (int k0 = 0; k0 < DD; k0 += 64) {
        uint32_t pa[2][8], pb[2][8];
#pragma unroll
        for (int ks = 0; ks < 2; ++ks) {
            float4v a4[4], b4[4];
#pragma unroll
            for (int l = 0; l < 4; ++l) {
                a4[l] = *(const float4v*)(gA + k0 + ks * 32 + l * 4);
                b4[l] = *(const float4v*)(gB + k0 + ks * 32 + l * 4);
            }
#pragma unroll
            for (int l = 0; l < 4; ++l) {
                pa[ks][2 * l]     = pk2h(a4[l][0], a4[l][1]);
                pa[ks][2 * l + 1] = pk2h(a4[l][2], a4[l][3]);
                pb[ks][2 * l]     = pk2h(b4[l][0], b4[l][1]);
                pb[ks][2 * l + 1] = pk2h(b4[l][2], b4[l][3]);
            }
        }
        __syncthreads();   // previous iteration's LDS reads complete
#pragma unroll
        for (int ks = 0; ks < 2; ++ks) {
            PackU p;
            p.u[0]=pa[ks][0]; p.u[1]=pa[ks][1]; p.u[2]=pa[ks][2]; p.u[3]=pa[ks][3];
            *(short8*)(&Ah[ks * 4096 + r * 32 + c0]) = p.s8;
            p.u[0]=pa[ks][4]; p.u[1]=pa[ks][5]; p.u[2]=pa[ks][6]; p.u[3]=pa[ks][7];
            *(short8*)(&Ah[ks * 4096 + r * 32 + c0 + 8]) = p.s8;
            p.u[0]=pb[ks][0]; p.u[1]=pb[ks][1]; p.u[2]=pb[ks][2]; p.u[3]=pb[ks][3];
            *(short8*)(&Bh[ks * 4096 + r * 32 + c0]) = p.s8;
            p.u[0]=pb[ks][4]; p.u[1]=pb[ks][5]; p.u[2]=pb[ks][6]; p.u[3]=pb[ks][7];
            *(short8*)(&Bh[ks * 4096 + r * 32 + c0 + 8]) = p.s8;
        }
        __syncthreads();

#pragma unroll
        for (int ks = 0; ks < 2; ++ks) {
            half8 fa[4], fb[4];
#pragma unroll
            for (int mt = 0; mt < 4; ++mt)
                fa[mt] = *(const half8*)(&Ah[ks * 4096 + (wm * 64 + mt * 16 + fm) * 32 + quad * 8]);
#pragma unroll
            for (int nt = 0; nt < 4; ++nt)
                fb[nt] = *(const half8*)(&Bh[ks * 4096 + (wn * 64 + nt * 16 + fm) * 32 + quad * 8]);
#pragma unroll
            for (int mt = 0; mt < 4; ++mt)
#pragma unroll
                for (int nt = 0; nt < 4; ++nt)
                    acc[mt][nt] = __builtin_amdgcn_mfma_f32_16x16x32_f16(fa[mt], fb[nt], acc[mt][nt], 0, 0, 0);
        }
    }

    uint16_t* qkb  = qk  + (size_t)b * SS * SS;
    uint16_t* qkTb = qkT + (size_t)b * SS * SS;
#pragma unroll
    for (int mt = 0; mt < 4; ++mt) {
#pragma unroll
        for (int nt = 0; nt < 4; ++nt) {
            const int srow = s0 + wm * 64 + mt * 16 + quad * 4;
            const int tcol = t0 + wn * 64 + nt * 16 + fm;
            uint32_t b0 = f2bf_rne(acc[mt][nt][0]);
            uint32_t b1 = f2bf_rne(acc[mt][nt][1]);
            uint32_t b2 = f2bf_rne(acc[mt][nt][2]);
            uint32_t b3 = f2bf_rne(acc[mt][nt][3]);
            qkb[(size_t)(srow + 0) * SS + tcol] = (uint16_t)b0;
            qkb[(size_t)(srow + 1) * SS + tcol] = (uint16_t)b1;
            qkb[(size_t)(srow + 2) * SS + tcol] = (uint16_t)b2;
            qkb[(size_t)(srow + 3) * SS + tcol] = (uint16_t)b3;
            uint2 pk = make_uint2(b0 | (b1 << 16), b2 | (b3 << 16));
            *(uint2*)(&qkTb[(size_t)tcol * SS + srow]) = pk;
        }
    }
}

// ---------------------------------------------------------------- softmax
// in-place: qk row -> softmax(0.125*row), bf16. qkT keeps the raw values.
__global__ __launch_bounds__(256) void softmax_inplace(uint16_t* __restrict__ qk)
{
    const size_t row = blockIdx.x;
    uint16_t* x = qk + row * SS;
    const int tid  = threadIdx.x;
    const int lane = tid & 63;
    const int wave = tid >> 6;

    uintx4 raw = *(const uintx4*)(x + tid * 8);
    float v[8];
#pragma unroll
    for (int i = 0; i < 4; ++i) {
        uint32_t u = raw[i];
        v[2 * i]     = bf2f(u & 0xffffu) * 0.125f;
        v[2 * i + 1] = bf2f(u >> 16) * 0.125f;
    }
    float m = v[0];
#pragma unroll
    for (int j = 1; j < 8; ++j) m = fmaxf(m, v[j]);
#pragma unroll
    for (int off = 1; off < 64; off <<= 1) m = fmaxf(m, __shfl_xor(m, off, 64));
    __shared__ float red[8];
    if (lane == 0) red[wave] = m;
    __syncthreads();
    m = fmaxf(fmaxf(red[0], red[1]), fmaxf(red[2], red[3]));

    float s = 0.f;
#pragma unroll
    for (int j = 0; j < 8; ++j) { v[j] = __expf(v[j] - m); s += v[j]; }
#pragma unroll
    for (int off = 1; off < 64; off <<= 1) s += __shfl_xor(s, off, 64);
    if (lane == 0) red[4 + wave] = s;
    __syncthreads();
    s = (red[4] + red[5]) + (red[6] + red[7]);
    const float inv = 1.0f / s;
#pragma unroll
    for (int i = 0; i < 4; ++i)
        raw[i] = f2bf_rne(v[2 * i] * inv) | (f2bf_rne(v[2 * i + 1] * inv) << 16);
    *(uintx4*)(x + tid * 8) = raw;
}

// ---------------------------------------------------------------- GEMM2
// out[s][t] = sum_u attn[s][u] * qkT[t][u]
// m97 structure + supertile swizzle + BK=64 (two sub-stages, one barrier pair)
__global__ __launch_bounds__(256, 2) void gemm2_kernel(
    const uint16_t* __restrict__ attn, const uint16_t* __restrict__ qkT,
    float* __restrict__ out)
{
    const int b = blockIdx.z;
    // 4x4 supertile remap: 16 consecutive dispatch IDs cover a 4x4 tile square.
    const int lin = blockIdx.y * 16 + blockIdx.x;
    const int sup = lin >> 4;
    const int inn = lin & 15;
    const int ty_ = (sup >> 2) * 4 + ((inn >> 2) & 3);
    const int tx_ = (sup & 3) * 4 + (inn & 3);
    const int s0 = ty_ * 128;
    const int t0 = tx_ * 128;

    const uint16_t* ab = attn + (size_t)b * SS * SS;
    const uint16_t* bb = qkT  + (size_t)b * SS * SS;

    __shared__ uint16_t As[2 * 128 * 32];   // two BK=32 sub-tiles
    __shared__ uint16_t Bs[2 * 128 * 32];

    const int tid  = threadIdx.x;
    const int lane = tid & 63;
    const int wave = tid >> 6;
    const int wm = wave >> 1, wn = wave & 1;
    const int fm = lane & 15, quad = lane >> 4;

    floatx4 acc[4][4];
#pragma unroll
    for (int i = 0; i < 4; ++i)
#pragma unroll
        for (int j = 0; j < 4; ++j)
            acc[i][j] = (floatx4)0.0f;

    const int c0i = wave * 128 + lane;
    const int c1i = c0i + 64;
    const int rA0 = c0i >> 2, pA0 = c0i & 3;
    const int rA1 = c1i >> 2, pA1 = c1i & 3;
    const int ldsOff0 = (wave * 128) * 8;        // halfs
    const int ldsOff1 = (wave * 128 + 64) * 8;

    for (int k0 = 0; k0 < SS; k0 += 64) {
        __syncthreads();   // previous iteration's LDS reads complete
#pragma unroll
        for (int ks = 0; ks < 2; ++ks) {
            const int kc = k0 + ks * 32;
            uint16_t* asub = &As[ks * 4096];
            uint16_t* bsub = &Bs[ks * 4096];
            __builtin_amdgcn_global_load_lds(
                (GLOBAL_AS void*)(ab + (size_t)(s0 + rA0) * SS + kc + pA0 * 8),
                (LDS_AS void*)(asub + ldsOff0), 16, 0, 0);
            __builtin_amdgcn_global_load_lds(
                (GLOBAL_AS void*)(ab + (size_t)(s0 + rA1) * SS + kc + pA1 * 8),
                (LDS_AS void*)(asub + ldsOff1), 16, 0, 0);
            __builtin_amdgcn_global_load_lds(
                (GLOBAL_AS void*)(bb + (size_t)(t0 + rA0) * SS + kc + pA0 * 8),
                (LDS_AS void*)(bsub + ldsOff0), 16, 0, 0);
            __builtin_amdgcn_global_load_lds(
                (GLOBAL_AS void*)(bb + (size_t)(t0 + rA1) * SS + kc + pA1 * 8),
                (LDS_AS void*)(bsub + ldsOff1), 16, 0, 0);
        }
        __syncthreads();   // drains vmcnt -> data resident in LDS

#pragma unroll
        for (int ks = 0; ks < 2; ++ks) {
            short8 fa[4], fb[4];
#pragma unroll
            for (int mt = 0; mt < 4; ++mt)
                fa[mt] = *(const short8*)(&As[ks * 4096 + (wm * 64 + mt * 16 + fm) * 32 + quad * 8]);
#pragma unroll
            for (int nt = 0; nt < 4; ++nt)
                fb[nt] = *(const short8*)(&Bs[ks * 4096 + (wn * 64 + nt * 16 + fm) * 32 + quad * 8]);
#pragma unroll
            for (int mt = 0; mt < 4; ++mt)
#pragma unroll
                for (int nt = 0; nt < 4; ++nt)
                    acc[mt][nt] = __builtin_amdgcn_mfma_f32_16x16x32_bf16(fa[mt], fb[nt], acc[mt][nt], 0, 0, 0);
        }
    }

    float* ob = out + (size_t)b * SS * SS;
#pragma unroll
    for (int mt = 0; mt < 4; ++mt) {
#pragma unroll
        for (int nt = 0; nt < 4; ++nt) {
            const int srow = s0 + wm * 64 + mt * 16 + quad * 4;
            const int tcol = t0 + wn * 64 + nt * 16 + fm;
#pragma unroll
            for (int reg = 0; reg < 4; ++reg)
                ob[(size_t)(srow + reg) * SS + tcol] = acc[mt][nt][reg];
        }
    }
}

extern "C" void kernel_launch(void* const* d_in, const int* in_sizes, int n_in,
                              void* d_out, int out_size, void* d_ws, size_t ws_size,
                              hipStream_t stream) {
    const float* q = (const float*)d_in[0];
    const float* k = (const float*)d_in[1];
    float* out = (float*)d_out;

    uint16_t* qk  = (uint16_t*)d_ws;
    uint16_t* qkT = qk + (size_t)BATCH * SS * SS;

    dim3 grid(SS / 128, SS / 128, BATCH);
    gemm1_kernel<<<grid, 256, 0, stream>>>(q, k, qk, qkT);
    softmax_inplace<<<dim3(BATCH * SS), 256, 0, stream>>>(qk);
    gemm2_kernel<<<grid, 256, 0, stream>>>(qk, qkT, out);
}